// Round 8
// baseline (1519.053 us; speedup 1.0000x reference)
//
#include <hip/hip_runtime.h>

#define Bn 256
#define Tn 512
#define Vn 64
#define Hn 256
#define INn 129
#define Cc 8                 // timesteps per chunk (fallback path)
#define NCH (Tn / Cc)
#define WU 68                // packed uints per W_ih row (136 f16 cols)
#define WSZ (768 * WU)       // uints for packed W_ih
#define GX_OFF (262144)      // byte offset of gx in ws
#define GX_BYTES ((size_t)Bn * Tn * 768 * 2)
#define AST 168              // A-tile LDS stride in halves (staging)
#define CST 264              // C-tile LDS stride in halves (epilogue transpose)

typedef __fp16 half2_t __attribute__((ext_vector_type(2)));
typedef __fp16 half8_t __attribute__((ext_vector_type(8)));
typedef float f32x4 __attribute__((ext_vector_type(4)));

static __device__ __forceinline__ unsigned int cvt2(float a, float b) {
  return __builtin_bit_cast(unsigned int, __builtin_amdgcn_cvt_pkrtz(a, b));
}

static __device__ __forceinline__ float dot2(unsigned int w, unsigned int x, float acc) {
#if __has_builtin(__builtin_amdgcn_fdot2)
  return __builtin_amdgcn_fdot2(__builtin_bit_cast(half2_t, w),
                                __builtin_bit_cast(half2_t, x), acc, false);
#else
  half2_t a = __builtin_bit_cast(half2_t, w);
  half2_t b = __builtin_bit_cast(half2_t, x);
  return acc + (float)a.x * (float)b.x + (float)a.y * (float)b.y;
#endif
}

// pair-sum across lanes 2i<->2i+1 (DPP quad_perm [1,0,3,2]) - fallback path only
static __device__ __forceinline__ float pair_sum(float v) {
#if __has_builtin(__builtin_amdgcn_update_dpp)
  int x = __builtin_amdgcn_update_dpp(0, __builtin_bit_cast(int, v), 0xB1, 0xF, 0xF, true);
  return v + __builtin_bit_cast(float, x);
#else
  int j = __builtin_amdgcn_ds_swizzle(__builtin_bit_cast(int, v), 0x041F);
  return v + __builtin_bit_cast(float, j);
#endif
}

static __device__ __forceinline__ float fast_exp2(float x) {
#if __has_builtin(__builtin_amdgcn_exp2f)
  return __builtin_amdgcn_exp2f(x);
#else
  return exp2f(x);
#endif
}
static __device__ __forceinline__ float fast_rcp(float x) {
#if __has_builtin(__builtin_amdgcn_rcpf)
  return __builtin_amdgcn_rcpf(x);
#else
  return 1.f / x;
#endif
}
static __device__ __forceinline__ float sigmoid_f(float x) {
  return fast_rcp(1.f + fast_exp2(-1.44269504f * x));
}
static __device__ __forceinline__ float tanh_f(float x) {
  return 1.f - 2.f * fast_rcp(1.f + fast_exp2(2.88539008f * x));
}

// extract half element r (0..3) from a uint2 of 4 packed f16
static __device__ __forceinline__ float half_at(uint2 u, int r) {
  half2_t p = __builtin_bit_cast(half2_t, (r < 2) ? u.x : u.y);
  return (float)p[r & 1];
}

// Pack W_ih (768x129 f32) into [768][68] f16-pair uints in workspace (cols >=129 zero).
__global__ void convert_wih(const float* __restrict__ W_ih, unsigned int* __restrict__ w16) {
  int idx = blockIdx.x * 256 + threadIdx.x;
  if (idx >= WSZ) return;
  int j = idx / WU, c = idx - j * WU;
  int col = 2 * c;
  float f0 = (col < INn) ? W_ih[(size_t)j * INn + col] : 0.f;
  float f1 = (col + 1 < INn) ? W_ih[(size_t)j * INn + col + 1] : 0.f;
  w16[idx] = cvt2(f0, f1);
}

// ---------------- GEMM: gx[b][t][n] = x[b][t].W_ih[n] + b_ih[n] (+ b_hh[n] for n<512) ----
__global__ __launch_bounds__(256, 4)
void gx_gemm(const float* __restrict__ times_in, const float* __restrict__ data_in,
             const float* __restrict__ mask_in, const unsigned int* __restrict__ w16,
             const float* __restrict__ b_ih, const float* __restrict__ b_hh,
             __fp16* __restrict__ gx) {
  __shared__ __align__(16) char raw[64 * CST * 2];  // staging (stride AST) then C-tile (stride CST)
  __fp16* xa = (__fp16*)raw;
  __fp16* ct = (__fp16*)raw;

  const int tid = threadIdx.x;
  const int bt = blockIdx.x;
  const int b = bt >> 3, tc = bt & 7;
  const int t0 = tc * 64;
  const int n0 = blockIdx.y * 256;

  {
    int r = tid >> 2, s = tid & 3;
    const float* src = (s < 2)
        ? data_in + ((size_t)b * Tn + t0 + r) * Vn + s * 32
        : mask_in + ((size_t)b * Tn + t0 + r) * Vn + (s - 2) * 32;
    unsigned int* dst = (unsigned int*)(xa + r * AST) + s * 16;
#pragma unroll
    for (int i = 0; i < 8; ++i) {
      float4 v = ((const float4*)src)[i];
      dst[2 * i] = cvt2(v.x, v.y);
      dst[2 * i + 1] = cvt2(v.z, v.w);
    }
  }
  if (tid < 64) {
    int g = t0 + tid;
    float tcur = times_in[(size_t)b * Tn + g];
    float d = (g < Tn - 1) ? times_in[(size_t)b * Tn + g + 1] - tcur : 0.f;
    unsigned int* p = (unsigned int*)(xa + tid * AST + 128);
    p[0] = cvt2(d, 0.f);
#pragma unroll
    for (int i = 1; i < 20; ++i) p[i] = 0u;
  }
  __syncthreads();

  const int w = tid >> 6, lane = tid & 63;
  const int m = lane & 15, q = lane >> 4;
  const int nw = n0 + w * 64;

  f32x4 acc[4][4];
#pragma unroll
  for (int i = 0; i < 4; ++i)
#pragma unroll
    for (int j = 0; j < 4; ++j) acc[i][j] = f32x4{0.f, 0.f, 0.f, 0.f};

#pragma unroll
  for (int kt = 0; kt < 5; ++kt) {
    const int k0 = kt * 32 + q * 8;
    half8_t bf[4], af[4];
#pragma unroll
    for (int nt = 0; nt < 4; ++nt) {
      int n = nw + nt * 16 + m;
      uint4 bv = *(const uint4*)(w16 + (size_t)n * WU + (k0 >> 1));
      bf[nt] = __builtin_bit_cast(half8_t, bv);
    }
#pragma unroll
    for (int mt = 0; mt < 4; ++mt) {
      uint4 av = *(const uint4*)(xa + (mt * 16 + m) * AST + k0);
      af[mt] = __builtin_bit_cast(half8_t, av);
    }
#pragma unroll
    for (int mt = 0; mt < 4; ++mt)
#pragma unroll
      for (int nt = 0; nt < 4; ++nt)
        acc[mt][nt] = __builtin_amdgcn_mfma_f32_16x16x32_f16(af[mt], bf[nt], acc[mt][nt], 0, 0, 0);
  }

  float bias[4];
#pragma unroll
  for (int nt = 0; nt < 4; ++nt) {
    int n = nw + nt * 16 + m;
    bias[nt] = b_ih[n] + ((n < 512) ? b_hh[n] : 0.f);  // fold r,z hh-biases
  }

  __syncthreads();
#pragma unroll
  for (int mt = 0; mt < 4; ++mt)
#pragma unroll
    for (int nt = 0; nt < 4; ++nt)
#pragma unroll
      for (int r = 0; r < 4; ++r)
        ct[(mt * 16 + q * 4 + r) * CST + w * 64 + nt * 16 + m] =
            (__fp16)(acc[mt][nt][r] + bias[nt]);
  __syncthreads();

  {
    const int tt = tid >> 2, qq = tid & 3;
    const uint4* src = (const uint4*)(ct + tt * CST) + qq * 8;
    uint4* dst = (uint4*)(gx + ((size_t)b * Tn + t0 + tt) * 768 + n0) + qq * 8;
#pragma unroll
    for (int i = 0; i < 8; ++i) dst[i] = src[i];
  }
}

// ---------------- Scan v5: MFMA hh-matvec, W_hh resident in AGPRs (copy-free) -------------
// R4-R7 evidence: the allocator parks large weight arrays in AGPRs and v_dot2 can't read
// them (per-use v_accvgpr_read tax). MFMA reads A-operands from AGPRs natively, so make the
// weights MFMA A-fragments. Wave w owns hidden rows 32w..32w+31 for all 3 gates -> gate
// values for unit j land in one lane: gates in-register, no reduction, 1 barrier/step.
__global__ __launch_bounds__(512, 2)
void gru_scan5(const float* __restrict__ times_in, const float* __restrict__ W_hh,
               const float* __restrict__ b_hh, const __fp16* __restrict__ gx,
               float* __restrict__ out) {
  __shared__ __align__(16) __fp16 h_buf[2][Hn];

  const int tid = threadIdx.x;
  const int b = blockIdx.x;
  const int w = tid >> 6;
  const int lane = tid & 63;
  const int m = lane & 15;  // A-operand row within 16-tile / C col (redundant)
  const int q = lane >> 4;  // k-subchunk / C row-quad
  const int rbase = 32 * w; // this wave's first hidden unit

  // ---- A-fragments: afr[gate][t2][kc] ; lane holds W_hh[g*256+rbase+16*t2+m][kc*32+q*8 ..+7]
  uint4 afr[3][2][8];
#pragma unroll
  for (int g = 0; g < 3; ++g)
#pragma unroll
    for (int t2 = 0; t2 < 2; ++t2) {
      const float* wrow = W_hh + (size_t)(g * 256 + rbase + 16 * t2 + m) * Hn + q * 8;
#pragma unroll
      for (int kc = 0; kc < 8; ++kc) {
        float4 v0 = *(const float4*)(wrow + kc * 32);
        float4 v1 = *(const float4*)(wrow + kc * 32 + 4);
        afr[g][t2][kc] = make_uint4(cvt2(v0.x, v0.y), cvt2(v0.z, v0.w),
                                    cvt2(v1.x, v1.y), cvt2(v1.z, v1.w));
      }
    }

  // n-gate hh bias for this lane's 8 hidden units (r,z biases folded into gx)
  float bhn[2][4];
#pragma unroll
  for (int t2 = 0; t2 < 2; ++t2) {
    float4 bv = *(const float4*)(b_hh + 512 + rbase + 16 * t2 + q * 4);
    bhn[t2][0] = bv.x; bhn[t2][1] = bv.y; bhn[t2][2] = bv.z; bhn[t2][3] = bv.w;
  }

  if (tid < Hn) h_buf[0][tid] = (__fp16)0.f;
  __syncthreads();

  const __fp16* gxb = gx + (size_t)b * Tn * 768;
  float hc[2][4] = {{0.f, 0.f, 0.f, 0.f}, {0.f, 0.f, 0.f, 0.f}};

#pragma unroll 1
  for (int t = 0; t < Tn; ++t) {
    const int cur = t & 1;

    // gx for this lane's 8 hidden units (issued early; L1-hit, hidden under MFMAs).
    // Uniform-address mt promotes to s_load.
    const __fp16* gpt = gxb + (size_t)t * 768 + rbase + q * 4;
    uint2 gxr[2], gxz[2], gxn[2];
#pragma unroll
    for (int t2 = 0; t2 < 2; ++t2) {
      gxr[t2] = *(const uint2*)(gpt + 16 * t2);
      gxz[t2] = *(const uint2*)(gpt + 256 + 16 * t2);
      gxn[t2] = *(const uint2*)(gpt + 512 + 16 * t2);
    }
    const float mt = times_in[(size_t)b * Tn + t];

    // hh matvec: 48 MFMAs, B = h broadcast (all 16 N-columns identical)
    f32x4 acc[3][2];
#pragma unroll
    for (int g = 0; g < 3; ++g)
#pragma unroll
      for (int t2 = 0; t2 < 2; ++t2) acc[g][t2] = f32x4{0.f, 0.f, 0.f, 0.f};

    const uint4* hb = (const uint4*)(&h_buf[cur][0]);
#pragma unroll
    for (int kc = 0; kc < 8; ++kc) {
      half8_t bfrag = __builtin_bit_cast(half8_t, hb[kc * 4 + q]);
#pragma unroll
      for (int g = 0; g < 3; ++g)
#pragma unroll
        for (int t2 = 0; t2 < 2; ++t2)
          acc[g][t2] = __builtin_amdgcn_mfma_f32_16x16x32_f16(
              __builtin_bit_cast(half8_t, afr[g][t2][kc]), bfrag, acc[g][t2], 0, 0, 0);
    }

    // gates fully in-register: unit j = rbase + 16*t2 + q*4 + r lives in this lane
#pragma unroll
    for (int t2 = 0; t2 < 2; ++t2)
#pragma unroll
      for (int r = 0; r < 4; ++r) {
        float rg = sigmoid_f(half_at(gxr[t2], r) + acc[0][t2][r]);
        float zg = sigmoid_f(half_at(gxz[t2], r) + acc[1][t2][r]);
        float ng = tanh_f(half_at(gxn[t2], r) + rg * (acc[2][t2][r] + bhn[t2][r]));
        float hN = (1.f - zg) * ng + zg * hc[t2][r];
        hc[t2][r] = (mt > 0.f) ? hN : hc[t2][r];
      }

    // publish h(t+1): col-0 lanes only (values replicated across the 16 cols)
    if (m == 0) {
#pragma unroll
      for (int t2 = 0; t2 < 2; ++t2) {
        uint2 hp;
        hp.x = cvt2(hc[t2][0], hc[t2][1]);
        hp.y = cvt2(hc[t2][2], hc[t2][3]);
        *(uint2*)&h_buf[cur ^ 1][rbase + 16 * t2 + q * 4] = hp;
      }
    }
    __syncthreads();
  }

  if (m == 0) {
#pragma unroll
    for (int t2 = 0; t2 < 2; ++t2) {
      float4 o;
      o.x = hc[t2][0]; o.y = hc[t2][1]; o.z = hc[t2][2]; o.w = hc[t2][3];
      *(float4*)(out + (size_t)b * Hn + rbase + 16 * t2 + q * 4) = o;
    }
  }
}

// ---------------- Fallback (R3): in-kernel phase A, used only if ws too small -------------
template <bool USE_WS>
static __device__ __forceinline__ void phaseA_pass(int col, const unsigned int* __restrict__ w16,
                                                   const float* __restrict__ W_ih,
                                                   const unsigned int* x_lds, float* a) {
  const uint4* wp = (const uint4*)(w16) + (size_t)col * (WU / 4);
  const float* wf = W_ih + (size_t)col * INn;
#pragma unroll 2
  for (int kp = 0; kp < 8; ++kp) {
    uint4 wa, wb;
    if constexpr (USE_WS) {
      wa = wp[2 * kp];
      wb = wp[2 * kp + 1];
    } else {
      const float* f = wf + 16 * kp;
      wa.x = cvt2(f[0], f[1]);   wa.y = cvt2(f[2], f[3]);
      wa.z = cvt2(f[4], f[5]);   wa.w = cvt2(f[6], f[7]);
      wb.x = cvt2(f[8], f[9]);   wb.y = cvt2(f[10], f[11]);
      wb.z = cvt2(f[12], f[13]); wb.w = cvt2(f[14], f[15]);
    }
#pragma unroll
    for (int t = 0; t < Cc; ++t) {
      const uint4* xp = (const uint4*)&x_lds[t * WU + kp * 8];
      uint4 xa = xp[0], xb = xp[1];
      a[t] = dot2(wa.x, xa.x, a[t]);
      a[t] = dot2(wa.y, xa.y, a[t]);
      a[t] = dot2(wa.z, xa.z, a[t]);
      a[t] = dot2(wa.w, xa.w, a[t]);
      a[t] = dot2(wb.x, xb.x, a[t]);
      a[t] = dot2(wb.y, xb.y, a[t]);
      a[t] = dot2(wb.z, xb.z, a[t]);
      a[t] = dot2(wb.w, xb.w, a[t]);
    }
  }
  uint4 wt;
  if constexpr (USE_WS) {
    wt = wp[16];
  } else {
    wt.x = cvt2(wf[128], 0.f); wt.y = 0u; wt.z = 0u; wt.w = 0u;
  }
#pragma unroll
  for (int t = 0; t < Cc; ++t) {
    uint4 xt = *(const uint4*)&x_lds[t * WU + 64];
    a[t] = dot2(wt.x, xt.x, a[t]);
    a[t] = dot2(wt.y, xt.y, a[t]);
  }
}

template <bool USE_WS>
__global__ __launch_bounds__(512, 2)
void gru_scan_fb(const float* __restrict__ times_in, const float* __restrict__ data_in,
                 const float* __restrict__ mask_in, const unsigned int* __restrict__ w16,
                 const float* __restrict__ W_ih, const float* __restrict__ W_hh,
                 const float* __restrict__ b_ih, const float* __restrict__ b_hh,
                 float* __restrict__ out) {
  __shared__ __align__(16) float gx_lds[Cc * 768];
  __shared__ __align__(16) unsigned int x_lds[Cc * WU];
  __shared__ __align__(16) __fp16 h_buf[2 * Hn];
  __shared__ __align__(16) float t_lds[Tn];

  const int tid = threadIdx.x;
  const int b = blockIdx.x;
  const int jg = tid >> 1;
  const int ks = tid & 1;

  t_lds[tid] = times_in[(size_t)b * Tn + tid];

  unsigned int whr[64], whz[64], whn[64];
  {
    const float* w0 = W_hh + (size_t)jg * Hn + ks * 128;
    const float* w1 = W_hh + (size_t)(jg + 256) * Hn + ks * 128;
    const float* w2 = W_hh + (size_t)(jg + 512) * Hn + ks * 128;
#pragma unroll
    for (int c = 0; c < 64; ++c) {
      whr[c] = cvt2(w0[2 * c], w0[2 * c + 1]);
      whz[c] = cvt2(w1[2 * c], w1[2 * c + 1]);
      whn[c] = cvt2(w2[2 * c], w2[2 * c + 1]);
    }
  }
  const float brh = b_hh[jg];
  const float bzh = b_hh[jg + 256];
  const float bhn = b_hh[jg + 512];
  const float bi1 = b_ih[tid];
  const float bi2 = (tid < 256) ? b_ih[512 + tid] : 0.f;

  h_buf[tid] = (__fp16)0.f;
  __syncthreads();

  float hcur = 0.f;
  int cur = 0;
#pragma unroll 1
  for (int ch = 0; ch < NCH; ++ch) {
    const int t0 = ch * Cc;
    {
      int t = tid >> 6;
      int c = tid & 63;
      const float* src = (c < 32)
          ? data_in + ((size_t)b * Tn + t0 + t) * Vn + 2 * c
          : mask_in + ((size_t)b * Tn + t0 + t) * Vn + 2 * (c - 32);
      float2 v = *(const float2*)src;
      x_lds[t * WU + c] = cvt2(v.x, v.y);
      if (tid < Cc) {
        int g = t0 + tid;
        float d = (g < Tn - 1) ? (t_lds[g + 1] - t_lds[g]) : 0.f;
        uint4 tl;
        tl.x = cvt2(d, 0.f); tl.y = 0u; tl.z = 0u; tl.w = 0u;
        *(uint4*)&x_lds[tid * WU + 64] = tl;
      }
    }
    __syncthreads();
    {
      float a[Cc];
#pragma unroll
      for (int t = 0; t < Cc; ++t) a[t] = bi1;
      phaseA_pass<USE_WS>(tid, w16, W_ih, x_lds, a);
#pragma unroll
      for (int t = 0; t < Cc; ++t) gx_lds[t * 768 + tid] = a[t];
      if (tid < 256) {
#pragma unroll
        for (int t = 0; t < Cc; ++t) a[t] = bi2;
        phaseA_pass<USE_WS>(512 + tid, w16, W_ih, x_lds, a);
#pragma unroll
        for (int t = 0; t < Cc; ++t) gx_lds[t * 768 + 512 + tid] = a[t];
      }
    }
    __syncthreads();
    for (int tt = 0; tt < Cc; ++tt) {
      float sr = 0.f, sz = 0.f, shn = 0.f;
      const uint4* hb = (const uint4*)(h_buf + cur * Hn + ks * 128);
#pragma unroll
      for (int c = 0; c < 16; ++c) {
        uint4 hv = hb[c];
        sr = dot2(whr[4 * c + 0], hv.x, sr);
        sz = dot2(whz[4 * c + 0], hv.x, sz);
        shn = dot2(whn[4 * c + 0], hv.x, shn);
        sr = dot2(whr[4 * c + 1], hv.y, sr);
        sz = dot2(whz[4 * c + 1], hv.y, sz);
        shn = dot2(whn[4 * c + 1], hv.y, shn);
        sr = dot2(whr[4 * c + 2], hv.z, sr);
        sz = dot2(whz[4 * c + 2], hv.z, sz);
        shn = dot2(whn[4 * c + 2], hv.z, shn);
        sr = dot2(whr[4 * c + 3], hv.w, sr);
        sz = dot2(whz[4 * c + 3], hv.w, sz);
        shn = dot2(whn[4 * c + 3], hv.w, shn);
      }
      float gxr = gx_lds[tt * 768 + jg];
      float gxz = gx_lds[tt * 768 + 256 + jg];
      float gxn = gx_lds[tt * 768 + 512 + jg];
      sr = pair_sum(sr);
      sz = pair_sum(sz);
      shn = pair_sum(shn);
      float r = sigmoid_f(gxr + sr + brh);
      float z = sigmoid_f(gxz + sz + bzh);
      float n = tanh_f(gxn + r * (shn + bhn));
      float hN = (1.f - z) * n + z * hcur;
      hcur = (t_lds[t0 + tt] > 0.f) ? hN : hcur;
      if (ks == 0) h_buf[(cur ^ 1) * Hn + jg] = (__fp16)hcur;
      __syncthreads();
      cur ^= 1;
    }
  }
  if (ks == 0) out[(size_t)b * Hn + jg] = hcur;
}

extern "C" void kernel_launch(void* const* d_in, const int* in_sizes, int n_in,
                              void* d_out, int out_size, void* d_ws, size_t ws_size,
                              hipStream_t stream) {
  const float* times_in = (const float*)d_in[0];
  const float* data_in = (const float*)d_in[1];
  const float* mask_in = (const float*)d_in[2];
  const float* W_ih = (const float*)d_in[3];
  const float* W_hh = (const float*)d_in[4];
  const float* b_ih = (const float*)d_in[5];
  const float* b_hh = (const float*)d_in[6];
  float* out = (float*)d_out;

  unsigned int* w16 = (unsigned int*)d_ws;
  __fp16* gx = (__fp16*)((char*)d_ws + GX_OFF);

  if (ws_size >= GX_OFF + GX_BYTES) {
    hipLaunchKernelGGL(convert_wih, dim3((WSZ + 255) / 256), dim3(256), 0, stream, W_ih, w16);
    hipLaunchKernelGGL(gx_gemm, dim3(2048, 3), dim3(256), 0, stream,
                       times_in, data_in, mask_in, w16, b_ih, b_hh, gx);
    hipLaunchKernelGGL(gru_scan5, dim3(Bn), dim3(512), 0, stream,
                       times_in, W_hh, b_hh, gx, out);
  } else if (ws_size >= (size_t)WSZ * 4) {
    hipLaunchKernelGGL(convert_wih, dim3((WSZ + 255) / 256), dim3(256), 0, stream, W_ih, w16);
    hipLaunchKernelGGL((gru_scan_fb<true>), dim3(Bn), dim3(512), 0, stream,
                       times_in, data_in, mask_in, w16, W_ih, W_hh, b_ih, b_hh, out);
  } else {
    hipLaunchKernelGGL((gru_scan_fb<false>), dim3(Bn), dim3(512), 0, stream,
                       times_in, data_in, mask_in, (const unsigned int*)nullptr, W_ih, W_hh,
                       b_ih, b_hh, out);
  }
}

// Round 9
// 969.689 us; speedup vs baseline: 1.5665x; 1.5665x over previous
//
#include <hip/hip_runtime.h>

#define Bn 256
#define Tn 512
#define Vn 64
#define Hn 256
#define INn 129
#define Cc 8                 // timesteps per chunk (fallback path)
#define NCH (Tn / Cc)
#define WU 68                // packed uints per W_ih row (136 f16 cols)
#define WSZ (768 * WU)       // uints for packed W_ih
#define GX_OFF (262144)      // byte offset of gx in ws
#define GX_BYTES ((size_t)Bn * Tn * 768 * 2)
#define AST 168              // A-tile LDS stride in halves (staging)
#define CST 264              // C-tile LDS stride in halves (epilogue transpose)

typedef __fp16 half2_t __attribute__((ext_vector_type(2)));
typedef __fp16 half8_t __attribute__((ext_vector_type(8)));
typedef float f32x4 __attribute__((ext_vector_type(4)));

static __device__ __forceinline__ unsigned int cvt2(float a, float b) {
  return __builtin_bit_cast(unsigned int, __builtin_amdgcn_cvt_pkrtz(a, b));
}

static __device__ __forceinline__ float dot2(unsigned int w, unsigned int x, float acc) {
#if __has_builtin(__builtin_amdgcn_fdot2)
  return __builtin_amdgcn_fdot2(__builtin_bit_cast(half2_t, w),
                                __builtin_bit_cast(half2_t, x), acc, false);
#else
  half2_t a = __builtin_bit_cast(half2_t, w);
  half2_t b = __builtin_bit_cast(half2_t, x);
  return acc + (float)a.x * (float)b.x + (float)a.y * (float)b.y;
#endif
}

// pair-sum across lanes 2i<->2i+1 (fallback path only)
static __device__ __forceinline__ float pair_sum(float v) {
#if __has_builtin(__builtin_amdgcn_update_dpp)
  int x = __builtin_amdgcn_update_dpp(0, __builtin_bit_cast(int, v), 0xB1, 0xF, 0xF, true);
  return v + __builtin_bit_cast(float, x);
#else
  int j = __builtin_amdgcn_ds_swizzle(__builtin_bit_cast(int, v), 0x041F);
  return v + __builtin_bit_cast(float, j);
#endif
}

// cross-lane add via bpermute (byte addr = lane*4)
static __device__ __forceinline__ float bperm_add(float v, int addr) {
  int j = __builtin_amdgcn_ds_bpermute(addr, __builtin_bit_cast(int, v));
  return v + __builtin_bit_cast(float, j);
}

static __device__ __forceinline__ float fast_exp2(float x) {
#if __has_builtin(__builtin_amdgcn_exp2f)
  return __builtin_amdgcn_exp2f(x);
#else
  return exp2f(x);
#endif
}
static __device__ __forceinline__ float fast_rcp(float x) {
#if __has_builtin(__builtin_amdgcn_rcpf)
  return __builtin_amdgcn_rcpf(x);
#else
  return 1.f / x;
#endif
}
static __device__ __forceinline__ float sigmoid_f(float x) {
  return fast_rcp(1.f + fast_exp2(-1.44269504f * x));
}
static __device__ __forceinline__ float tanh_f(float x) {
  return 1.f - 2.f * fast_rcp(1.f + fast_exp2(2.88539008f * x));
}

// Pack W_ih (768x129 f32) into [768][68] f16-pair uints in workspace (cols >=129 zero).
__global__ void convert_wih(const float* __restrict__ W_ih, unsigned int* __restrict__ w16) {
  int idx = blockIdx.x * 256 + threadIdx.x;
  if (idx >= WSZ) return;
  int j = idx / WU, c = idx - j * WU;
  int col = 2 * c;
  float f0 = (col < INn) ? W_ih[(size_t)j * INn + col] : 0.f;
  float f1 = (col + 1 < INn) ? W_ih[(size_t)j * INn + col + 1] : 0.f;
  w16[idx] = cvt2(f0, f1);
}

// ---------------- GEMM: gx[b][t][n] = x[b][t].W_ih[n] + b_ih[n] (+ b_hh[n] for n<512) ----
__global__ __launch_bounds__(256, 4)
void gx_gemm(const float* __restrict__ times_in, const float* __restrict__ data_in,
             const float* __restrict__ mask_in, const unsigned int* __restrict__ w16,
             const float* __restrict__ b_ih, const float* __restrict__ b_hh,
             __fp16* __restrict__ gx) {
  __shared__ __align__(16) char raw[64 * CST * 2];
  __fp16* xa = (__fp16*)raw;
  __fp16* ct = (__fp16*)raw;

  const int tid = threadIdx.x;
  const int bt = blockIdx.x;
  const int b = bt >> 3, tc = bt & 7;
  const int t0 = tc * 64;
  const int n0 = blockIdx.y * 256;

  {
    int r = tid >> 2, s = tid & 3;
    const float* src = (s < 2)
        ? data_in + ((size_t)b * Tn + t0 + r) * Vn + s * 32
        : mask_in + ((size_t)b * Tn + t0 + r) * Vn + (s - 2) * 32;
    unsigned int* dst = (unsigned int*)(xa + r * AST) + s * 16;
#pragma unroll
    for (int i = 0; i < 8; ++i) {
      float4 v = ((const float4*)src)[i];
      dst[2 * i] = cvt2(v.x, v.y);
      dst[2 * i + 1] = cvt2(v.z, v.w);
    }
  }
  if (tid < 64) {
    int g = t0 + tid;
    float tcur = times_in[(size_t)b * Tn + g];
    float d = (g < Tn - 1) ? times_in[(size_t)b * Tn + g + 1] - tcur : 0.f;
    unsigned int* p = (unsigned int*)(xa + tid * AST + 128);
    p[0] = cvt2(d, 0.f);
#pragma unroll
    for (int i = 1; i < 20; ++i) p[i] = 0u;
  }
  __syncthreads();

  const int w = tid >> 6, lane = tid & 63;
  const int m = lane & 15, q = lane >> 4;
  const int nw = n0 + w * 64;

  f32x4 acc[4][4];
#pragma unroll
  for (int i = 0; i < 4; ++i)
#pragma unroll
    for (int j = 0; j < 4; ++j) acc[i][j] = f32x4{0.f, 0.f, 0.f, 0.f};

#pragma unroll
  for (int kt = 0; kt < 5; ++kt) {
    const int k0 = kt * 32 + q * 8;
    half8_t bf[4], af[4];
#pragma unroll
    for (int nt = 0; nt < 4; ++nt) {
      int n = nw + nt * 16 + m;
      uint4 bv = *(const uint4*)(w16 + (size_t)n * WU + (k0 >> 1));
      bf[nt] = __builtin_bit_cast(half8_t, bv);
    }
#pragma unroll
    for (int mt = 0; mt < 4; ++mt) {
      uint4 av = *(const uint4*)(xa + (mt * 16 + m) * AST + k0);
      af[mt] = __builtin_bit_cast(half8_t, av);
    }
#pragma unroll
    for (int mt = 0; mt < 4; ++mt)
#pragma unroll
      for (int nt = 0; nt < 4; ++nt)
        acc[mt][nt] = __builtin_amdgcn_mfma_f32_16x16x32_f16(af[mt], bf[nt], acc[mt][nt], 0, 0, 0);
  }

  float bias[4];
#pragma unroll
  for (int nt = 0; nt < 4; ++nt) {
    int n = nw + nt * 16 + m;
    bias[nt] = b_ih[n] + ((n < 512) ? b_hh[n] : 0.f);
  }

  __syncthreads();
#pragma unroll
  for (int mt = 0; mt < 4; ++mt)
#pragma unroll
    for (int nt = 0; nt < 4; ++nt)
#pragma unroll
      for (int r = 0; r < 4; ++r)
        ct[(mt * 16 + q * 4 + r) * CST + w * 64 + nt * 16 + m] =
            (__fp16)(acc[mt][nt][r] + bias[nt]);
  __syncthreads();

  {
    const int tt = tid >> 2, qq = tid & 3;
    const uint4* src = (const uint4*)(ct + tt * CST) + qq * 8;
    uint4* dst = (uint4*)(gx + ((size_t)b * Tn + t0 + tt) * 768 + n0) + qq * 8;
#pragma unroll
    for (int i = 0; i < 8; ++i) dst[i] = src[i];
  }
}

// ---------------- Scan v6: hybrid — MFMA(r,z from AGPR) + dot2(n in arch), pipes overlap --
// R8 lesson: 3-gate A-frags (192 regs) overflow the 128-AGPR half -> scratch spill (WRITE
// 92MB). Here r,z A-frags = 32 uint4 = exactly 128 AGPR; n-gate = 64 arch uints consumed by
// v_dot2 (native arch reads, no copy tax). dot2 k-subset == this lane's B-fragment halves,
// so the n-dots reuse the MFMA B registers: zero extra LDS reads. m114: pipes co-schedule.
__global__ __launch_bounds__(512, 2)
void gru_scan6(const float* __restrict__ times_in, const float* __restrict__ W_hh,
               const float* __restrict__ b_hh, const __fp16* __restrict__ gx,
               float* __restrict__ out) {
  __shared__ __align__(16) __fp16 h_buf[2][Hn];
  __shared__ __align__(16) float rz_lds[512];
  __shared__ __align__(16) float t_lds[Tn];

  const int tid = threadIdx.x;
  const int b = blockIdx.x;
  const int w = tid >> 6;
  const int lane = tid & 63;
  const int m = lane & 15;   // A row-in-tile / C col(redundant)
  const int q = lane >> 4;   // k-subchunk / C row-quad
  const int rbase = 32 * w;  // wave's first hidden unit
  const int u0 = rbase + 2 * m;  // this lane's n-gate / consumer unit pair

  t_lds[tid] = times_in[(size_t)b * Tn + tid];

  // r,z A-fragments (AGPR): afr[g][t2][kc]; lane holds W_hh[g*256+rbase+16*t2+m][kc*32+q*8..+7]
  uint4 afr[2][2][8];
#pragma unroll
  for (int g = 0; g < 2; ++g)
#pragma unroll
    for (int t2 = 0; t2 < 2; ++t2) {
      const float* wrow = W_hh + (size_t)(g * 256 + rbase + 16 * t2 + m) * Hn + q * 8;
#pragma unroll
      for (int kc = 0; kc < 8; ++kc) {
        float4 v0 = *(const float4*)(wrow + kc * 32);
        float4 v1 = *(const float4*)(wrow + kc * 32 + 4);
        afr[g][t2][kc] = make_uint4(cvt2(v0.x, v0.y), cvt2(v0.z, v0.w),
                                    cvt2(v1.x, v1.y), cvt2(v1.z, v1.w));
      }
    }

  // n-gate dot2 weights (arch): units u0,u0+1; k-subset = halves kc*32+q*8..+7
  unsigned int wn[2][32];
#pragma unroll
  for (int e = 0; e < 2; ++e) {
    const float* wrow = W_hh + (size_t)(512 + u0 + e) * Hn + q * 8;
#pragma unroll
    for (int kc = 0; kc < 8; ++kc) {
      float4 v0 = *(const float4*)(wrow + kc * 32);
      float4 v1 = *(const float4*)(wrow + kc * 32 + 4);
      wn[e][kc * 4 + 0] = cvt2(v0.x, v0.y);
      wn[e][kc * 4 + 1] = cvt2(v0.z, v0.w);
      wn[e][kc * 4 + 2] = cvt2(v1.x, v1.y);
      wn[e][kc * 4 + 3] = cvt2(v1.z, v1.w);
    }
  }
  const float2 bhn = *(const float2*)(b_hh + 512 + u0);

  if (tid < Hn) h_buf[0][tid] = (__fp16)0.f;
  __syncthreads();

  const __fp16* gxb = gx + (size_t)b * Tn * 768;
  const int a16 = (lane ^ 16) << 2;
  const int a32 = (lane ^ 32) << 2;
  float h0p = 0.f, h1p = 0.f;

#pragma unroll 1
  for (int t = 0; t < Tn; ++t) {
    const int cur = t & 1;

    // gx for phase 2 (unit pair: one uint = both halves), issued early — ~1500 cyc cover
    const __fp16* gp = gxb + (size_t)t * 768 + u0;
    const unsigned int gxr = *(const unsigned int*)(gp);
    const unsigned int gxz = *(const unsigned int*)(gp + 256);
    const unsigned int gxn = *(const unsigned int*)(gp + 512);
    const float mt = t_lds[t];

    f32x4 acc[2][2];
    acc[0][0] = f32x4{0.f, 0.f, 0.f, 0.f};
    acc[0][1] = f32x4{0.f, 0.f, 0.f, 0.f};
    acc[1][0] = f32x4{0.f, 0.f, 0.f, 0.f};
    acc[1][1] = f32x4{0.f, 0.f, 0.f, 0.f};
    float sn0 = 0.f, sn1 = 0.f;

    const uint4* hb = (const uint4*)(&h_buf[cur][0]);
    uint4 bcur = hb[q];
#pragma unroll
    for (int kc = 0; kc < 8; ++kc) {
      uint4 bnext;
      if (kc < 7) bnext = hb[(kc + 1) * 4 + q];
      half8_t bf = __builtin_bit_cast(half8_t, bcur);
      acc[0][0] = __builtin_amdgcn_mfma_f32_16x16x32_f16(
          __builtin_bit_cast(half8_t, afr[0][0][kc]), bf, acc[0][0], 0, 0, 0);
      acc[0][1] = __builtin_amdgcn_mfma_f32_16x16x32_f16(
          __builtin_bit_cast(half8_t, afr[0][1][kc]), bf, acc[0][1], 0, 0, 0);
      acc[1][0] = __builtin_amdgcn_mfma_f32_16x16x32_f16(
          __builtin_bit_cast(half8_t, afr[1][0][kc]), bf, acc[1][0], 0, 0, 0);
      acc[1][1] = __builtin_amdgcn_mfma_f32_16x16x32_f16(
          __builtin_bit_cast(half8_t, afr[1][1][kc]), bf, acc[1][1], 0, 0, 0);
      sn0 = dot2(wn[0][kc * 4 + 0], bcur.x, sn0);
      sn1 = dot2(wn[1][kc * 4 + 0], bcur.x, sn1);
      sn0 = dot2(wn[0][kc * 4 + 1], bcur.y, sn0);
      sn1 = dot2(wn[1][kc * 4 + 1], bcur.y, sn1);
      sn0 = dot2(wn[0][kc * 4 + 2], bcur.z, sn0);
      sn1 = dot2(wn[1][kc * 4 + 2], bcur.z, sn1);
      sn0 = dot2(wn[0][kc * 4 + 3], bcur.w, sn0);
      sn1 = dot2(wn[1][kc * 4 + 3], bcur.w, sn1);
      bcur = bnext;
    }

    // n-sum reduction over the 4-lane q-group (lanes m, m+16, m+32, m+48)
    sn0 = bperm_add(sn0, a16);
    sn0 = bperm_add(sn0, a32);
    sn1 = bperm_add(sn1, a16);
    sn1 = bperm_add(sn1, a32);

    // publish r,z pre-activations (m==0 lanes; C layout row = q*4+reg)
    if (m == 0) {
      *(f32x4*)&rz_lds[rbase + q * 4] = acc[0][0];
      *(f32x4*)&rz_lds[rbase + 16 + q * 4] = acc[0][1];
      *(f32x4*)&rz_lds[256 + rbase + q * 4] = acc[1][0];
      *(f32x4*)&rz_lds[256 + rbase + 16 + q * 4] = acc[1][1];
    }
    __syncthreads();

    // phase 2: q==0 lanes finalize their unit pair
    if (q == 0) {
      float2 rp = *(const float2*)&rz_lds[u0];
      float2 zp = *(const float2*)&rz_lds[256 + u0];
      half2_t gr = __builtin_bit_cast(half2_t, gxr);
      half2_t gz = __builtin_bit_cast(half2_t, gxz);
      half2_t gn = __builtin_bit_cast(half2_t, gxn);
      float r0 = sigmoid_f((float)gr[0] + rp.x);
      float r1 = sigmoid_f((float)gr[1] + rp.y);
      float z0 = sigmoid_f((float)gz[0] + zp.x);
      float z1 = sigmoid_f((float)gz[1] + zp.y);
      float n0 = tanh_f((float)gn[0] + r0 * (sn0 + bhn.x));
      float n1 = tanh_f((float)gn[1] + r1 * (sn1 + bhn.y));
      float hN0 = (1.f - z0) * n0 + z0 * h0p;
      float hN1 = (1.f - z1) * n1 + z1 * h1p;
      h0p = (mt > 0.f) ? hN0 : h0p;
      h1p = (mt > 0.f) ? hN1 : h1p;
      *(unsigned int*)&h_buf[cur ^ 1][u0] = cvt2(h0p, h1p);
    }
    __syncthreads();
  }

  if (q == 0) {
    float2 o;
    o.x = h0p;
    o.y = h1p;
    *(float2*)(out + (size_t)b * Hn + u0) = o;
  }
}

// ---------------- Fallback (R3): in-kernel phase A, used only if ws too small -------------
template <bool USE_WS>
static __device__ __forceinline__ void phaseA_pass(int col, const unsigned int* __restrict__ w16,
                                                   const float* __restrict__ W_ih,
                                                   const unsigned int* x_lds, float* a) {
  const uint4* wp = (const uint4*)(w16) + (size_t)col * (WU / 4);
  const float* wf = W_ih + (size_t)col * INn;
#pragma unroll 2
  for (int kp = 0; kp < 8; ++kp) {
    uint4 wa, wb;
    if constexpr (USE_WS) {
      wa = wp[2 * kp];
      wb = wp[2 * kp + 1];
    } else {
      const float* f = wf + 16 * kp;
      wa.x = cvt2(f[0], f[1]);   wa.y = cvt2(f[2], f[3]);
      wa.z = cvt2(f[4], f[5]);   wa.w = cvt2(f[6], f[7]);
      wb.x = cvt2(f[8], f[9]);   wb.y = cvt2(f[10], f[11]);
      wb.z = cvt2(f[12], f[13]); wb.w = cvt2(f[14], f[15]);
    }
#pragma unroll
    for (int t = 0; t < Cc; ++t) {
      const uint4* xp = (const uint4*)&x_lds[t * WU + kp * 8];
      uint4 xa = xp[0], xb = xp[1];
      a[t] = dot2(wa.x, xa.x, a[t]);
      a[t] = dot2(wa.y, xa.y, a[t]);
      a[t] = dot2(wa.z, xa.z, a[t]);
      a[t] = dot2(wa.w, xa.w, a[t]);
      a[t] = dot2(wb.x, xb.x, a[t]);
      a[t] = dot2(wb.y, xb.y, a[t]);
      a[t] = dot2(wb.z, xb.z, a[t]);
      a[t] = dot2(wb.w, xb.w, a[t]);
    }
  }
  uint4 wt;
  if constexpr (USE_WS) {
    wt = wp[16];
  } else {
    wt.x = cvt2(wf[128], 0.f); wt.y = 0u; wt.z = 0u; wt.w = 0u;
  }
#pragma unroll
  for (int t = 0; t < Cc; ++t) {
    uint4 xt = *(const uint4*)&x_lds[t * WU + 64];
    a[t] = dot2(wt.x, xt.x, a[t]);
    a[t] = dot2(wt.y, xt.y, a[t]);
  }
}

template <bool USE_WS>
__global__ __launch_bounds__(512, 2)
void gru_scan_fb(const float* __restrict__ times_in, const float* __restrict__ data_in,
                 const float* __restrict__ mask_in, const unsigned int* __restrict__ w16,
                 const float* __restrict__ W_ih, const float* __restrict__ W_hh,
                 const float* __restrict__ b_ih, const float* __restrict__ b_hh,
                 float* __restrict__ out) {
  __shared__ __align__(16) float gx_lds[Cc * 768];
  __shared__ __align__(16) unsigned int x_lds[Cc * WU];
  __shared__ __align__(16) __fp16 h_buf[2 * Hn];
  __shared__ __align__(16) float t_lds[Tn];

  const int tid = threadIdx.x;
  const int b = blockIdx.x;
  const int jg = tid >> 1;
  const int ks = tid & 1;

  t_lds[tid] = times_in[(size_t)b * Tn + tid];

  unsigned int whr[64], whz[64], whn[64];
  {
    const float* w0 = W_hh + (size_t)jg * Hn + ks * 128;
    const float* w1 = W_hh + (size_t)(jg + 256) * Hn + ks * 128;
    const float* w2 = W_hh + (size_t)(jg + 512) * Hn + ks * 128;
#pragma unroll
    for (int c = 0; c < 64; ++c) {
      whr[c] = cvt2(w0[2 * c], w0[2 * c + 1]);
      whz[c] = cvt2(w1[2 * c], w1[2 * c + 1]);
      whn[c] = cvt2(w2[2 * c], w2[2 * c + 1]);
    }
  }
  const float brh = b_hh[jg];
  const float bzh = b_hh[jg + 256];
  const float bhn = b_hh[jg + 512];
  const float bi1 = b_ih[tid];
  const float bi2 = (tid < 256) ? b_ih[512 + tid] : 0.f;

  h_buf[tid] = (__fp16)0.f;
  __syncthreads();

  float hcur = 0.f;
  int cur = 0;
#pragma unroll 1
  for (int ch = 0; ch < NCH; ++ch) {
    const int t0 = ch * Cc;
    {
      int t = tid >> 6;
      int c = tid & 63;
      const float* src = (c < 32)
          ? data_in + ((size_t)b * Tn + t0 + t) * Vn + 2 * c
          : mask_in + ((size_t)b * Tn + t0 + t) * Vn + 2 * (c - 32);
      float2 v = *(const float2*)src;
      x_lds[t * WU + c] = cvt2(v.x, v.y);
      if (tid < Cc) {
        int g = t0 + tid;
        float d = (g < Tn - 1) ? (t_lds[g + 1] - t_lds[g]) : 0.f;
        uint4 tl;
        tl.x = cvt2(d, 0.f); tl.y = 0u; tl.z = 0u; tl.w = 0u;
        *(uint4*)&x_lds[tid * WU + 64] = tl;
      }
    }
    __syncthreads();
    {
      float a[Cc];
#pragma unroll
      for (int t = 0; t < Cc; ++t) a[t] = bi1;
      phaseA_pass<USE_WS>(tid, w16, W_ih, x_lds, a);
#pragma unroll
      for (int t = 0; t < Cc; ++t) gx_lds[t * 768 + tid] = a[t];
      if (tid < 256) {
#pragma unroll
        for (int t = 0; t < Cc; ++t) a[t] = bi2;
        phaseA_pass<USE_WS>(512 + tid, w16, W_ih, x_lds, a);
#pragma unroll
        for (int t = 0; t < Cc; ++t) gx_lds[t * 768 + 512 + tid] = a[t];
      }
    }
    __syncthreads();
    for (int tt = 0; tt < Cc; ++tt) {
      float sr = 0.f, sz = 0.f, shn = 0.f;
      const uint4* hb = (const uint4*)(h_buf + cur * Hn + ks * 128);
#pragma unroll
      for (int c = 0; c < 16; ++c) {
        uint4 hv = hb[c];
        sr = dot2(whr[4 * c + 0], hv.x, sr);
        sz = dot2(whz[4 * c + 0], hv.x, sz);
        shn = dot2(whn[4 * c + 0], hv.x, shn);
        sr = dot2(whr[4 * c + 1], hv.y, sr);
        sz = dot2(whz[4 * c + 1], hv.y, sz);
        shn = dot2(whn[4 * c + 1], hv.y, shn);
        sr = dot2(whr[4 * c + 2], hv.z, sr);
        sz = dot2(whz[4 * c + 2], hv.z, sz);
        shn = dot2(whn[4 * c + 2], hv.z, shn);
        sr = dot2(whr[4 * c + 3], hv.w, sr);
        sz = dot2(whz[4 * c + 3], hv.w, sz);
        shn = dot2(whn[4 * c + 3], hv.w, shn);
      }
      float gxr = gx_lds[tt * 768 + jg];
      float gxz = gx_lds[tt * 768 + 256 + jg];
      float gxn = gx_lds[tt * 768 + 512 + jg];
      sr = pair_sum(sr);
      sz = pair_sum(sz);
      shn = pair_sum(shn);
      float r = sigmoid_f(gxr + sr + brh);
      float z = sigmoid_f(gxz + sz + bzh);
      float n = tanh_f(gxn + r * (shn + bhn));
      float hN = (1.f - z) * n + z * hcur;
      hcur = (t_lds[t0 + tt] > 0.f) ? hN : hcur;
      if (ks == 0) h_buf[(cur ^ 1) * Hn + jg] = (__fp16)hcur;
      __syncthreads();
      cur ^= 1;
    }
  }
  if (ks == 0) out[(size_t)b * Hn + jg] = hcur;
}

extern "C" void kernel_launch(void* const* d_in, const int* in_sizes, int n_in,
                              void* d_out, int out_size, void* d_ws, size_t ws_size,
                              hipStream_t stream) {
  const float* times_in = (const float*)d_in[0];
  const float* data_in = (const float*)d_in[1];
  const float* mask_in = (const float*)d_in[2];
  const float* W_ih = (const float*)d_in[3];
  const float* W_hh = (const float*)d_in[4];
  const float* b_ih = (const float*)d_in[5];
  const float* b_hh = (const float*)d_in[6];
  float* out = (float*)d_out;

  unsigned int* w16 = (unsigned int*)d_ws;
  __fp16* gx = (__fp16*)((char*)d_ws + GX_OFF);

  if (ws_size >= GX_OFF + GX_BYTES) {
    hipLaunchKernelGGL(convert_wih, dim3((WSZ + 255) / 256), dim3(256), 0, stream, W_ih, w16);
    hipLaunchKernelGGL(gx_gemm, dim3(2048, 3), dim3(256), 0, stream,
                       times_in, data_in, mask_in, w16, b_ih, b_hh, gx);
    hipLaunchKernelGGL(gru_scan6, dim3(Bn), dim3(512), 0, stream,
                       times_in, W_hh, b_hh, gx, out);
  } else if (ws_size >= (size_t)WSZ * 4) {
    hipLaunchKernelGGL(convert_wih, dim3((WSZ + 255) / 256), dim3(256), 0, stream, W_ih, w16);
    hipLaunchKernelGGL((gru_scan_fb<true>), dim3(Bn), dim3(512), 0, stream,
                       times_in, data_in, mask_in, w16, W_ih, W_hh, b_ih, b_hh, out);
  } else {
    hipLaunchKernelGGL((gru_scan_fb<false>), dim3(Bn), dim3(512), 0, stream,
                       times_in, data_in, mask_in, (const unsigned int*)nullptr, W_ih, W_hh,
                       b_ih, b_hh, out);
  }
}

// Round 10
// 787.659 us; speedup vs baseline: 1.9286x; 1.2311x over previous
//
#include <hip/hip_runtime.h>

#define Bn 256
#define Tn 512
#define Vn 64
#define Hn 256
#define INn 129
#define Cc 8                 // timesteps per chunk (fallback path)
#define NCH (Tn / Cc)
#define WU 68                // packed uints per W_ih row (136 f16 cols)
#define WSZ (768 * WU)       // uints for packed W_ih
#define GX_OFF (262144)      // byte offset of gx in ws
#define GX_BYTES ((size_t)Bn * Tn * 768 * 2)
#define AST 168              // A-tile LDS stride in halves (staging)
#define CST 264              // C-tile LDS stride in halves (epilogue transpose)

typedef __fp16 half2_t __attribute__((ext_vector_type(2)));
typedef __fp16 half8_t __attribute__((ext_vector_type(8)));
typedef float f32x4 __attribute__((ext_vector_type(4)));

static __device__ __forceinline__ unsigned int cvt2(float a, float b) {
  return __builtin_bit_cast(unsigned int, __builtin_amdgcn_cvt_pkrtz(a, b));
}

// builtin dot2 (fallback path)
static __device__ __forceinline__ float dot2(unsigned int w, unsigned int x, float acc) {
#if __has_builtin(__builtin_amdgcn_fdot2)
  return __builtin_amdgcn_fdot2(__builtin_bit_cast(half2_t, w),
                                __builtin_bit_cast(half2_t, x), acc, false);
#else
  half2_t a = __builtin_bit_cast(half2_t, w);
  half2_t b = __builtin_bit_cast(half2_t, x);
  return acc + (float)a.x * (float)b.x + (float)a.y * (float)b.y;
#endif
}

// asm dot2 with "v" constraints: forces w,x,acc into ARCH VGPRs (AGPR placement illegal).
// R5-R9 evidence: compiler parks large weight arrays in AGPRs and pays v_accvgpr_read per
// use; this constraint removes that option for the scan's weight operands.
static __device__ __forceinline__ float dot2a(unsigned int w, unsigned int x, float acc) {
  asm("v_dot2_f32_f16 %0, %1, %2, %0" : "+v"(acc) : "v"(w), "v"(x));
  return acc;
}

// pair-sum across lanes 2i<->2i+1 (DPP quad_perm [1,0,3,2])
static __device__ __forceinline__ float pair_sum(float v) {
#if __has_builtin(__builtin_amdgcn_update_dpp)
  int x = __builtin_amdgcn_update_dpp(0, __builtin_bit_cast(int, v), 0xB1, 0xF, 0xF, true);
  return v + __builtin_bit_cast(float, x);
#else
  int j = __builtin_amdgcn_ds_swizzle(__builtin_bit_cast(int, v), 0x041F);
  return v + __builtin_bit_cast(float, j);
#endif
}

static __device__ __forceinline__ float fast_exp2(float x) {
#if __has_builtin(__builtin_amdgcn_exp2f)
  return __builtin_amdgcn_exp2f(x);
#else
  return exp2f(x);
#endif
}
static __device__ __forceinline__ float fast_rcp(float x) {
#if __has_builtin(__builtin_amdgcn_rcpf)
  return __builtin_amdgcn_rcpf(x);
#else
  return 1.f / x;
#endif
}
static __device__ __forceinline__ float sigmoid_f(float x) {
  return fast_rcp(1.f + fast_exp2(-1.44269504f * x));
}
static __device__ __forceinline__ float tanh_f(float x) {
  return 1.f - 2.f * fast_rcp(1.f + fast_exp2(2.88539008f * x));
}

// Pack W_ih (768x129 f32) into [768][68] f16-pair uints in workspace (cols >=129 zero).
__global__ void convert_wih(const float* __restrict__ W_ih, unsigned int* __restrict__ w16) {
  int idx = blockIdx.x * 256 + threadIdx.x;
  if (idx >= WSZ) return;
  int j = idx / WU, c = idx - j * WU;
  int col = 2 * c;
  float f0 = (col < INn) ? W_ih[(size_t)j * INn + col] : 0.f;
  float f1 = (col + 1 < INn) ? W_ih[(size_t)j * INn + col + 1] : 0.f;
  w16[idx] = cvt2(f0, f1);
}

// ---------------- GEMM: gx[b][t][n] = x[b][t].W_ih[n] + b_ih[n] (+ b_hh[n] for n<512) ----
__global__ __launch_bounds__(256, 4)
void gx_gemm(const float* __restrict__ times_in, const float* __restrict__ data_in,
             const float* __restrict__ mask_in, const unsigned int* __restrict__ w16,
             const float* __restrict__ b_ih, const float* __restrict__ b_hh,
             __fp16* __restrict__ gx) {
  __shared__ __align__(16) char raw[64 * CST * 2];
  __fp16* xa = (__fp16*)raw;
  __fp16* ct = (__fp16*)raw;

  const int tid = threadIdx.x;
  const int bt = blockIdx.x;
  const int b = bt >> 3, tc = bt & 7;
  const int t0 = tc * 64;
  const int n0 = blockIdx.y * 256;

  {
    int r = tid >> 2, s = tid & 3;
    const float* src = (s < 2)
        ? data_in + ((size_t)b * Tn + t0 + r) * Vn + s * 32
        : mask_in + ((size_t)b * Tn + t0 + r) * Vn + (s - 2) * 32;
    unsigned int* dst = (unsigned int*)(xa + r * AST) + s * 16;
#pragma unroll
    for (int i = 0; i < 8; ++i) {
      float4 v = ((const float4*)src)[i];
      dst[2 * i] = cvt2(v.x, v.y);
      dst[2 * i + 1] = cvt2(v.z, v.w);
    }
  }
  if (tid < 64) {
    int g = t0 + tid;
    float tcur = times_in[(size_t)b * Tn + g];
    float d = (g < Tn - 1) ? times_in[(size_t)b * Tn + g + 1] - tcur : 0.f;
    unsigned int* p = (unsigned int*)(xa + tid * AST + 128);
    p[0] = cvt2(d, 0.f);
#pragma unroll
    for (int i = 1; i < 20; ++i) p[i] = 0u;
  }
  __syncthreads();

  const int w = tid >> 6, lane = tid & 63;
  const int m = lane & 15, q = lane >> 4;
  const int nw = n0 + w * 64;

  f32x4 acc[4][4];
#pragma unroll
  for (int i = 0; i < 4; ++i)
#pragma unroll
    for (int j = 0; j < 4; ++j) acc[i][j] = f32x4{0.f, 0.f, 0.f, 0.f};

#pragma unroll
  for (int kt = 0; kt < 5; ++kt) {
    const int k0 = kt * 32 + q * 8;
    half8_t bf[4], af[4];
#pragma unroll
    for (int nt = 0; nt < 4; ++nt) {
      int n = nw + nt * 16 + m;
      uint4 bv = *(const uint4*)(w16 + (size_t)n * WU + (k0 >> 1));
      bf[nt] = __builtin_bit_cast(half8_t, bv);
    }
#pragma unroll
    for (int mt = 0; mt < 4; ++mt) {
      uint4 av = *(const uint4*)(xa + (mt * 16 + m) * AST + k0);
      af[mt] = __builtin_bit_cast(half8_t, av);
    }
#pragma unroll
    for (int mt = 0; mt < 4; ++mt)
#pragma unroll
      for (int nt = 0; nt < 4; ++nt)
        acc[mt][nt] = __builtin_amdgcn_mfma_f32_16x16x32_f16(af[mt], bf[nt], acc[mt][nt], 0, 0, 0);
  }

  float bias[4];
#pragma unroll
  for (int nt = 0; nt < 4; ++nt) {
    int n = nw + nt * 16 + m;
    bias[nt] = b_ih[n] + ((n < 512) ? b_hh[n] : 0.f);  // fold r,z hh-biases
  }

  __syncthreads();
#pragma unroll
  for (int mt = 0; mt < 4; ++mt)
#pragma unroll
    for (int nt = 0; nt < 4; ++nt)
#pragma unroll
      for (int r = 0; r < 4; ++r)
        ct[(mt * 16 + q * 4 + r) * CST + w * 64 + nt * 16 + m] =
            (__fp16)(acc[mt][nt][r] + bias[nt]);
  __syncthreads();

  {
    const int tt = tid >> 2, qq = tid & 3;
    const uint4* src = (const uint4*)(ct + tt * CST) + qq * 8;
    uint4* dst = (uint4*)(gx + ((size_t)b * Tn + t0 + tt) * 768 + n0) + qq * 8;
#pragma unroll
    for (int i = 0; i < 8; ++i) dst[i] = src[i];
  }
}

// ---------------- Scan v7: dot2 via asm "v" (arch-forced weights) + masked-step skip ------
__global__ __launch_bounds__(512, 1)
void gru_scan7(const float* __restrict__ times_in, const float* __restrict__ W_hh,
               const float* __restrict__ b_hh, const __fp16* __restrict__ gx,
               float* __restrict__ out) {
  __shared__ __align__(16) __fp16 h_buf[2 * Hn];
  __shared__ __align__(16) float t_lds[Tn];

  const int tid = threadIdx.x;
  const int b = blockIdx.x;
  const int jg = tid >> 1;
  const int ks = tid & 1;

  t_lds[tid] = times_in[(size_t)b * Tn + tid];

  unsigned int whr[64], whz[64], whn[64];
  {
    const float* w0 = W_hh + (size_t)jg * Hn + ks * 128;
    const float* w1 = W_hh + (size_t)(jg + 256) * Hn + ks * 128;
    const float* w2 = W_hh + (size_t)(jg + 512) * Hn + ks * 128;
#pragma unroll
    for (int c = 0; c < 64; ++c) {
      whr[c] = cvt2(w0[2 * c], w0[2 * c + 1]);
      whz[c] = cvt2(w1[2 * c], w1[2 * c + 1]);
      whn[c] = cvt2(w2[2 * c], w2[2 * c + 1]);
    }
  }
  const float bhn = b_hh[jg + 512];  // r,z hh-biases folded into gx by the GEMM

  h_buf[tid] = (__fp16)0.f;  // both ping-pong buffers
  __syncthreads();

  const __fp16* gxb = gx + (size_t)b * Tn * 768;
  float hcur = 0.f;
  int cur = 0;

  float gr = (float)gxb[jg], gz = (float)gxb[256 + jg], gn = (float)gxb[512 + jg];
  float mt = t_lds[0];

#pragma unroll 1
  for (int t = 0; t < Tn; ++t) {
    // prefetch step t+1 (clamped); issued before compute, consumed next iteration
    const int tn = (t + 1 < Tn) ? (t + 1) : (Tn - 1);
    const __fp16* p = gxb + (size_t)tn * 768;
    __fp16 pr = p[jg], pz = p[256 + jg], pn = p[512 + jg];
    float mtn = t_lds[tn];

    // block-uniform skip: t_exist false => h unchanged, no LDS touched, no barrier
    if (mt > 0.f) {
      const uint4* hb = (const uint4*)(h_buf + cur * Hn) + ks * 16;

      float sr = 0.f, sz = 0.f, shn = 0.f;
      uint4 p0 = hb[0], p1 = hb[1];
#pragma unroll
      for (int cc = 0; cc < 8; ++cc) {
        uint4 q0 = p0, q1 = p1;
        if (cc < 7) { q0 = hb[2 * cc + 2]; q1 = hb[2 * cc + 3]; }
        const int cb = cc * 8;
        sr = dot2a(whr[cb + 0], p0.x, sr);
        sz = dot2a(whz[cb + 0], p0.x, sz);
        shn = dot2a(whn[cb + 0], p0.x, shn);
        sr = dot2a(whr[cb + 1], p0.y, sr);
        sz = dot2a(whz[cb + 1], p0.y, sz);
        shn = dot2a(whn[cb + 1], p0.y, shn);
        sr = dot2a(whr[cb + 2], p0.z, sr);
        sz = dot2a(whz[cb + 2], p0.z, sz);
        shn = dot2a(whn[cb + 2], p0.z, shn);
        sr = dot2a(whr[cb + 3], p0.w, sr);
        sz = dot2a(whz[cb + 3], p0.w, sz);
        shn = dot2a(whn[cb + 3], p0.w, shn);
        sr = dot2a(whr[cb + 4], p1.x, sr);
        sz = dot2a(whz[cb + 4], p1.x, sz);
        shn = dot2a(whn[cb + 4], p1.x, shn);
        sr = dot2a(whr[cb + 5], p1.y, sr);
        sz = dot2a(whz[cb + 5], p1.y, sz);
        shn = dot2a(whn[cb + 5], p1.y, shn);
        sr = dot2a(whr[cb + 6], p1.z, sr);
        sz = dot2a(whz[cb + 6], p1.z, sz);
        shn = dot2a(whn[cb + 6], p1.z, shn);
        sr = dot2a(whr[cb + 7], p1.w, sr);
        sz = dot2a(whz[cb + 7], p1.w, sz);
        shn = dot2a(whn[cb + 7], p1.w, shn);
        p0 = q0; p1 = q1;
      }

      sr = pair_sum(sr);
      sz = pair_sum(sz);
      shn = pair_sum(shn);

      float r = sigmoid_f(gr + sr);
      float z = sigmoid_f(gz + sz);
      float n = tanh_f(gn + r * (shn + bhn));
      hcur = (1.f - z) * n + z * hcur;

      if (ks == 0) h_buf[(cur ^ 1) * Hn + jg] = (__fp16)hcur;
      __syncthreads();
      cur ^= 1;
    }

    gr = (float)pr; gz = (float)pz; gn = (float)pn; mt = mtn;
  }

  if (ks == 0) out[(size_t)b * Hn + jg] = hcur;
}

// ---------------- Fallback (R3): in-kernel phase A, used only if ws too small -------------
template <bool USE_WS>
static __device__ __forceinline__ void phaseA_pass(int col, const unsigned int* __restrict__ w16,
                                                   const float* __restrict__ W_ih,
                                                   const unsigned int* x_lds, float* a) {
  const uint4* wp = (const uint4*)(w16) + (size_t)col * (WU / 4);
  const float* wf = W_ih + (size_t)col * INn;
#pragma unroll 2
  for (int kp = 0; kp < 8; ++kp) {
    uint4 wa, wb;
    if constexpr (USE_WS) {
      wa = wp[2 * kp];
      wb = wp[2 * kp + 1];
    } else {
      const float* f = wf + 16 * kp;
      wa.x = cvt2(f[0], f[1]);   wa.y = cvt2(f[2], f[3]);
      wa.z = cvt2(f[4], f[5]);   wa.w = cvt2(f[6], f[7]);
      wb.x = cvt2(f[8], f[9]);   wb.y = cvt2(f[10], f[11]);
      wb.z = cvt2(f[12], f[13]); wb.w = cvt2(f[14], f[15]);
    }
#pragma unroll
    for (int t = 0; t < Cc; ++t) {
      const uint4* xp = (const uint4*)&x_lds[t * WU + kp * 8];
      uint4 xa = xp[0], xb = xp[1];
      a[t] = dot2(wa.x, xa.x, a[t]);
      a[t] = dot2(wa.y, xa.y, a[t]);
      a[t] = dot2(wa.z, xa.z, a[t]);
      a[t] = dot2(wa.w, xa.w, a[t]);
      a[t] = dot2(wb.x, xb.x, a[t]);
      a[t] = dot2(wb.y, xb.y, a[t]);
      a[t] = dot2(wb.z, xb.z, a[t]);
      a[t] = dot2(wb.w, xb.w, a[t]);
    }
  }
  uint4 wt;
  if constexpr (USE_WS) {
    wt = wp[16];
  } else {
    wt.x = cvt2(wf[128], 0.f); wt.y = 0u; wt.z = 0u; wt.w = 0u;
  }
#pragma unroll
  for (int t = 0; t < Cc; ++t) {
    uint4 xt = *(const uint4*)&x_lds[t * WU + 64];
    a[t] = dot2(wt.x, xt.x, a[t]);
    a[t] = dot2(wt.y, xt.y, a[t]);
  }
}

template <bool USE_WS>
__global__ __launch_bounds__(512, 2)
void gru_scan_fb(const float* __restrict__ times_in, const float* __restrict__ data_in,
                 const float* __restrict__ mask_in, const unsigned int* __restrict__ w16,
                 const float* __restrict__ W_ih, const float* __restrict__ W_hh,
                 const float* __restrict__ b_ih, const float* __restrict__ b_hh,
                 float* __restrict__ out) {
  __shared__ __align__(16) float gx_lds[Cc * 768];
  __shared__ __align__(16) unsigned int x_lds[Cc * WU];
  __shared__ __align__(16) __fp16 h_buf[2 * Hn];
  __shared__ __align__(16) float t_lds[Tn];

  const int tid = threadIdx.x;
  const int b = blockIdx.x;
  const int jg = tid >> 1;
  const int ks = tid & 1;

  t_lds[tid] = times_in[(size_t)b * Tn + tid];

  unsigned int whr[64], whz[64], whn[64];
  {
    const float* w0 = W_hh + (size_t)jg * Hn + ks * 128;
    const float* w1 = W_hh + (size_t)(jg + 256) * Hn + ks * 128;
    const float* w2 = W_hh + (size_t)(jg + 512) * Hn + ks * 128;
#pragma unroll
    for (int c = 0; c < 64; ++c) {
      whr[c] = cvt2(w0[2 * c], w0[2 * c + 1]);
      whz[c] = cvt2(w1[2 * c], w1[2 * c + 1]);
      whn[c] = cvt2(w2[2 * c], w2[2 * c + 1]);
    }
  }
  const float brh = b_hh[jg];
  const float bzh = b_hh[jg + 256];
  const float bhn = b_hh[jg + 512];
  const float bi1 = b_ih[tid];
  const float bi2 = (tid < 256) ? b_ih[512 + tid] : 0.f;

  h_buf[tid] = (__fp16)0.f;
  __syncthreads();

  float hcur = 0.f;
  int cur = 0;
#pragma unroll 1
  for (int ch = 0; ch < NCH; ++ch) {
    const int t0 = ch * Cc;
    {
      int t = tid >> 6;
      int c = tid & 63;
      const float* src = (c < 32)
          ? data_in + ((size_t)b * Tn + t0 + t) * Vn + 2 * c
          : mask_in + ((size_t)b * Tn + t0 + t) * Vn + 2 * (c - 32);
      float2 v = *(const float2*)src;
      x_lds[t * WU + c] = cvt2(v.x, v.y);
      if (tid < Cc) {
        int g = t0 + tid;
        float d = (g < Tn - 1) ? (t_lds[g + 1] - t_lds[g]) : 0.f;
        uint4 tl;
        tl.x = cvt2(d, 0.f); tl.y = 0u; tl.z = 0u; tl.w = 0u;
        *(uint4*)&x_lds[tid * WU + 64] = tl;
      }
    }
    __syncthreads();
    {
      float a[Cc];
#pragma unroll
      for (int t = 0; t < Cc; ++t) a[t] = bi1;
      phaseA_pass<USE_WS>(tid, w16, W_ih, x_lds, a);
#pragma unroll
      for (int t = 0; t < Cc; ++t) gx_lds[t * 768 + tid] = a[t];
      if (tid < 256) {
#pragma unroll
        for (int t = 0; t < Cc; ++t) a[t] = bi2;
        phaseA_pass<USE_WS>(512 + tid, w16, W_ih, x_lds, a);
#pragma unroll
        for (int t = 0; t < Cc; ++t) gx_lds[t * 768 + 512 + tid] = a[t];
      }
    }
    __syncthreads();
    for (int tt = 0; tt < Cc; ++tt) {
      float sr = 0.f, sz = 0.f, shn = 0.f;
      const uint4* hb = (const uint4*)(h_buf + cur * Hn + ks * 128);
#pragma unroll
      for (int c = 0; c < 16; ++c) {
        uint4 hv = hb[c];
        sr = dot2(whr[4 * c + 0], hv.x, sr);
        sz = dot2(whz[4 * c + 0], hv.x, sz);
        shn = dot2(whn[4 * c + 0], hv.x, shn);
        sr = dot2(whr[4 * c + 1], hv.y, sr);
        sz = dot2(whz[4 * c + 1], hv.y, sz);
        shn = dot2(whn[4 * c + 1], hv.y, shn);
        sr = dot2(whr[4 * c + 2], hv.z, sr);
        sz = dot2(whz[4 * c + 2], hv.z, sz);
        shn = dot2(whn[4 * c + 2], hv.z, shn);
        sr = dot2(whr[4 * c + 3], hv.w, sr);
        sz = dot2(whz[4 * c + 3], hv.w, sz);
        shn = dot2(whn[4 * c + 3], hv.w, shn);
      }
      float gxr = gx_lds[tt * 768 + jg];
      float gxz = gx_lds[tt * 768 + 256 + jg];
      float gxn = gx_lds[tt * 768 + 512 + jg];
      sr = pair_sum(sr);
      sz = pair_sum(sz);
      shn = pair_sum(shn);
      float r = sigmoid_f(gxr + sr + brh);
      float z = sigmoid_f(gxz + sz + bzh);
      float n = tanh_f(gxn + r * (shn + bhn));
      float hN = (1.f - z) * n + z * hcur;
      hcur = (t_lds[t0 + tt] > 0.f) ? hN : hcur;
      if (ks == 0) h_buf[(cur ^ 1) * Hn + jg] = (__fp16)hcur;
      __syncthreads();
      cur ^= 1;
    }
  }
  if (ks == 0) out[(size_t)b * Hn + jg] = hcur;
}

extern "C" void kernel_launch(void* const* d_in, const int* in_sizes, int n_in,
                              void* d_out, int out_size, void* d_ws, size_t ws_size,
                              hipStream_t stream) {
  const float* times_in = (const float*)d_in[0];
  const float* data_in = (const float*)d_in[1];
  const float* mask_in = (const float*)d_in[2];
  const float* W_ih = (const float*)d_in[3];
  const float* W_hh = (const float*)d_in[4];
  const float* b_ih = (const float*)d_in[5];
  const float* b_hh = (const float*)d_in[6];
  float* out = (float*)d_out;

  unsigned int* w16 = (unsigned int*)d_ws;
  __fp16* gx = (__fp16*)((char*)d_ws + GX_OFF);

  if (ws_size >= GX_OFF + GX_BYTES) {
    hipLaunchKernelGGL(convert_wih, dim3((WSZ + 255) / 256), dim3(256), 0, stream, W_ih, w16);
    hipLaunchKernelGGL(gx_gemm, dim3(2048, 3), dim3(256), 0, stream,
                       times_in, data_in, mask_in, w16, b_ih, b_hh, gx);
    hipLaunchKernelGGL(gru_scan7, dim3(Bn), dim3(512), 0, stream,
                       times_in, W_hh, b_hh, gx, out);
  } else if (ws_size >= (size_t)WSZ * 4) {
    hipLaunchKernelGGL(convert_wih, dim3((WSZ + 255) / 256), dim3(256), 0, stream, W_ih, w16);
    hipLaunchKernelGGL((gru_scan_fb<true>), dim3(Bn), dim3(512), 0, stream,
                       times_in, data_in, mask_in, w16, W_ih, W_hh, b_ih, b_hh, out);
  } else {
    hipLaunchKernelGGL((gru_scan_fb<false>), dim3(Bn), dim3(512), 0, stream,
                       times_in, data_in, mask_in, (const unsigned int*)nullptr, W_ih, W_hh,
                       b_ih, b_hh, out);
  }
}

// Round 11
// 754.289 us; speedup vs baseline: 2.0139x; 1.0442x over previous
//
#include <hip/hip_runtime.h>

#define Bn 256
#define Tn 512
#define Vn 64
#define Hn 256
#define INn 129
#define Cc 8                 // timesteps per chunk (fallback path)
#define NCH (Tn / Cc)
#define WU 68                // packed uints per W_ih row (136 f16 cols)
#define WSZ (768 * WU)       // uints for packed W_ih
#define GX_OFF (262144)      // byte offset of gx in ws
#define GX_BYTES ((size_t)Bn * Tn * 768 * 2)
#define AST 168              // A-tile LDS stride in halves (staging)
#define CST 264              // C-tile LDS stride in halves (epilogue transpose)

typedef __fp16 half2_t __attribute__((ext_vector_type(2)));
typedef __fp16 half8_t __attribute__((ext_vector_type(8)));
typedef float f32x4 __attribute__((ext_vector_type(4)));

static __device__ __forceinline__ unsigned int cvt2(float a, float b) {
  return __builtin_bit_cast(unsigned int, __builtin_amdgcn_cvt_pkrtz(a, b));
}

// builtin dot2 (fallback path)
static __device__ __forceinline__ float dot2(unsigned int w, unsigned int x, float acc) {
#if __has_builtin(__builtin_amdgcn_fdot2)
  return __builtin_amdgcn_fdot2(__builtin_bit_cast(half2_t, w),
                                __builtin_bit_cast(half2_t, x), acc, false);
#else
  half2_t a = __builtin_bit_cast(half2_t, w);
  half2_t b = __builtin_bit_cast(half2_t, x);
  return acc + (float)a.x * (float)b.x + (float)a.y * (float)b.y;
#endif
}

// asm dot2 (scan path; identical perf to builtin — kept from R10)
static __device__ __forceinline__ float dot2a(unsigned int w, unsigned int x, float acc) {
  asm("v_dot2_f32_f16 %0, %1, %2, %0" : "+v"(acc) : "v"(w), "v"(x));
  return acc;
}

// pair-sum across lanes 2i<->2i+1 (DPP quad_perm [1,0,3,2])
static __device__ __forceinline__ float pair_sum(float v) {
#if __has_builtin(__builtin_amdgcn_update_dpp)
  int x = __builtin_amdgcn_update_dpp(0, __builtin_bit_cast(int, v), 0xB1, 0xF, 0xF, true);
  return v + __builtin_bit_cast(float, x);
#else
  int j = __builtin_amdgcn_ds_swizzle(__builtin_bit_cast(int, v), 0x041F);
  return v + __builtin_bit_cast(float, j);
#endif
}

static __device__ __forceinline__ float fast_exp2(float x) {
#if __has_builtin(__builtin_amdgcn_exp2f)
  return __builtin_amdgcn_exp2f(x);
#else
  return exp2f(x);
#endif
}
static __device__ __forceinline__ float fast_rcp(float x) {
#if __has_builtin(__builtin_amdgcn_rcpf)
  return __builtin_amdgcn_rcpf(x);
#else
  return 1.f / x;
#endif
}
static __device__ __forceinline__ float sigmoid_f(float x) {
  return fast_rcp(1.f + fast_exp2(-1.44269504f * x));
}
static __device__ __forceinline__ float tanh_f(float x) {
  return 1.f - 2.f * fast_rcp(1.f + fast_exp2(2.88539008f * x));
}

// Pack W_ih (768x129 f32) into [768][68] f16-pair uints in workspace (cols >=129 zero).
__global__ void convert_wih(const float* __restrict__ W_ih, unsigned int* __restrict__ w16) {
  int idx = blockIdx.x * 256 + threadIdx.x;
  if (idx >= WSZ) return;
  int j = idx / WU, c = idx - j * WU;
  int col = 2 * c;
  float f0 = (col < INn) ? W_ih[(size_t)j * INn + col] : 0.f;
  float f1 = (col + 1 < INn) ? W_ih[(size_t)j * INn + col + 1] : 0.f;
  w16[idx] = cvt2(f0, f1);
}

// ---------------- GEMM: gx[b][t][n] = x[b][t].W_ih[n] + b_ih[n] (+ b_hh[n] for n<512) ----
__global__ __launch_bounds__(256, 4)
void gx_gemm(const float* __restrict__ times_in, const float* __restrict__ data_in,
             const float* __restrict__ mask_in, const unsigned int* __restrict__ w16,
             const float* __restrict__ b_ih, const float* __restrict__ b_hh,
             __fp16* __restrict__ gx) {
  __shared__ __align__(16) char raw[64 * CST * 2];
  __fp16* xa = (__fp16*)raw;
  __fp16* ct = (__fp16*)raw;

  const int tid = threadIdx.x;
  const int bt = blockIdx.x;
  const int b = bt >> 3, tc = bt & 7;
  const int t0 = tc * 64;
  const int n0 = blockIdx.y * 256;

  {
    int r = tid >> 2, s = tid & 3;
    const float* src = (s < 2)
        ? data_in + ((size_t)b * Tn + t0 + r) * Vn + s * 32
        : mask_in + ((size_t)b * Tn + t0 + r) * Vn + (s - 2) * 32;
    unsigned int* dst = (unsigned int*)(xa + r * AST) + s * 16;
#pragma unroll
    for (int i = 0; i < 8; ++i) {
      float4 v = ((const float4*)src)[i];
      dst[2 * i] = cvt2(v.x, v.y);
      dst[2 * i + 1] = cvt2(v.z, v.w);
    }
  }
  if (tid < 64) {
    int g = t0 + tid;
    float tcur = times_in[(size_t)b * Tn + g];
    float d = (g < Tn - 1) ? times_in[(size_t)b * Tn + g + 1] - tcur : 0.f;
    unsigned int* p = (unsigned int*)(xa + tid * AST + 128);
    p[0] = cvt2(d, 0.f);
#pragma unroll
    for (int i = 1; i < 20; ++i) p[i] = 0u;
  }
  __syncthreads();

  const int w = tid >> 6, lane = tid & 63;
  const int m = lane & 15, q = lane >> 4;
  const int nw = n0 + w * 64;

  f32x4 acc[4][4];
#pragma unroll
  for (int i = 0; i < 4; ++i)
#pragma unroll
    for (int j = 0; j < 4; ++j) acc[i][j] = f32x4{0.f, 0.f, 0.f, 0.f};

#pragma unroll
  for (int kt = 0; kt < 5; ++kt) {
    const int k0 = kt * 32 + q * 8;
    half8_t bf[4], af[4];
#pragma unroll
    for (int nt = 0; nt < 4; ++nt) {
      int n = nw + nt * 16 + m;
      uint4 bv = *(const uint4*)(w16 + (size_t)n * WU + (k0 >> 1));
      bf[nt] = __builtin_bit_cast(half8_t, bv);
    }
#pragma unroll
    for (int mt = 0; mt < 4; ++mt) {
      uint4 av = *(const uint4*)(xa + (mt * 16 + m) * AST + k0);
      af[mt] = __builtin_bit_cast(half8_t, av);
    }
#pragma unroll
    for (int mt = 0; mt < 4; ++mt)
#pragma unroll
      for (int nt = 0; nt < 4; ++nt)
        acc[mt][nt] = __builtin_amdgcn_mfma_f32_16x16x32_f16(af[mt], bf[nt], acc[mt][nt], 0, 0, 0);
  }

  float bias[4];
#pragma unroll
  for (int nt = 0; nt < 4; ++nt) {
    int n = nw + nt * 16 + m;
    bias[nt] = b_ih[n] + ((n < 512) ? b_hh[n] : 0.f);  // fold r,z hh-biases
  }

  __syncthreads();
#pragma unroll
  for (int mt = 0; mt < 4; ++mt)
#pragma unroll
    for (int nt = 0; nt < 4; ++nt)
#pragma unroll
      for (int r = 0; r < 4; ++r)
        ct[(mt * 16 + q * 4 + r) * CST + w * 64 + nt * 16 + m] =
            (__fp16)(acc[mt][nt][r] + bias[nt]);
  __syncthreads();

  {
    const int tt = tid >> 2, qq = tid & 3;
    const uint4* src = (const uint4*)(ct + tt * CST) + qq * 8;
    uint4* dst = (uint4*)(gx + ((size_t)b * Tn + t0 + tt) * 768 + n0) + qq * 8;
#pragma unroll
    for (int i = 0; i < 8; ++i) dst[i] = src[i];
  }
}

// ---------------- Scan v8: compacted active-step iteration (skip is free) -----------------
// R10 lesson: per-step mask branch saved only 2% (prefetch + loop-carried mt dependency
// still paid). Here inactive steps are removed up front: ballot+popc prefix builds act[],
// the loop runs exactly nact (~460) productive iterations with no mask logic at all.
__global__ __launch_bounds__(512, 1)
void gru_scan8(const float* __restrict__ times_in, const float* __restrict__ W_hh,
               const float* __restrict__ b_hh, const __fp16* __restrict__ gx,
               float* __restrict__ out) {
  __shared__ __align__(16) __fp16 h_buf[2 * Hn];
  __shared__ short act[Tn];
  __shared__ int wave_cnt[8];
  __shared__ int nact_s;

  const int tid = threadIdx.x;
  const int b = blockIdx.x;
  const int jg = tid >> 1;
  const int ks = tid & 1;
  const int lane = tid & 63;
  const int wv = tid >> 6;

  // ---- compact active timesteps (one-time) ----
  {
    float tv = times_in[(size_t)b * Tn + tid];
    bool on = tv > 0.f;
    unsigned long long mask = __ballot(on);
    int within = __popcll(mask & ((1ull << lane) - 1ull));
    if (lane == 0) wave_cnt[wv] = __popcll(mask);
    __syncthreads();
    int off = 0;
#pragma unroll
    for (int i = 0; i < 8; ++i) off += (i < wv) ? wave_cnt[i] : 0;
    if (on) act[off + within] = (short)tid;
    if (tid == 0) {
      int n = 0;
#pragma unroll
      for (int i = 0; i < 8; ++i) n += wave_cnt[i];
      nact_s = n;
    }
  }

  // ---- register-resident W_hh (f16 pairs; AGPR-resident per R4-R10 — copy tax accepted) --
  unsigned int whr[64], whz[64], whn[64];
  {
    const float* w0 = W_hh + (size_t)jg * Hn + ks * 128;
    const float* w1 = W_hh + (size_t)(jg + 256) * Hn + ks * 128;
    const float* w2 = W_hh + (size_t)(jg + 512) * Hn + ks * 128;
#pragma unroll
    for (int c = 0; c < 64; ++c) {
      whr[c] = cvt2(w0[2 * c], w0[2 * c + 1]);
      whz[c] = cvt2(w1[2 * c], w1[2 * c + 1]);
      whn[c] = cvt2(w2[2 * c], w2[2 * c + 1]);
    }
  }
  const float bhn = b_hh[jg + 512];  // r,z hh-biases folded into gx by the GEMM

  h_buf[tid] = (__fp16)0.f;  // both ping-pong buffers
  __syncthreads();

  const int nact = nact_s;
  const __fp16* gxb = gx + (size_t)b * Tn * 768;
  float hcur = 0.f;
  int cur = 0;

  if (nact > 0) {
    int t0i = act[0];
    float gr = (float)gxb[(size_t)t0i * 768 + jg];
    float gz = (float)gxb[(size_t)t0i * 768 + 256 + jg];
    float gn = (float)gxb[(size_t)t0i * 768 + 512 + jg];

#pragma unroll 1
    for (int i = 0; i < nact; ++i) {
      // prefetch next active step's gx (clamped; last-iter values unused)
      const int ni = (i + 1 < nact) ? (i + 1) : (nact - 1);
      const int tnx = act[ni];
      const __fp16* p = gxb + (size_t)tnx * 768;
      __fp16 pr = p[jg], pz = p[256 + jg], pn = p[512 + jg];

      const uint4* hb = (const uint4*)(h_buf + cur * Hn) + ks * 16;

      float sr = 0.f, sz = 0.f, shn = 0.f;
      uint4 p0 = hb[0], p1 = hb[1];
#pragma unroll
      for (int cc = 0; cc < 8; ++cc) {
        uint4 q0 = p0, q1 = p1;
        if (cc < 7) { q0 = hb[2 * cc + 2]; q1 = hb[2 * cc + 3]; }
        const int cb = cc * 8;
        sr = dot2a(whr[cb + 0], p0.x, sr);
        sz = dot2a(whz[cb + 0], p0.x, sz);
        shn = dot2a(whn[cb + 0], p0.x, shn);
        sr = dot2a(whr[cb + 1], p0.y, sr);
        sz = dot2a(whz[cb + 1], p0.y, sz);
        shn = dot2a(whn[cb + 1], p0.y, shn);
        sr = dot2a(whr[cb + 2], p0.z, sr);
        sz = dot2a(whz[cb + 2], p0.z, sz);
        shn = dot2a(whn[cb + 2], p0.z, shn);
        sr = dot2a(whr[cb + 3], p0.w, sr);
        sz = dot2a(whz[cb + 3], p0.w, sz);
        shn = dot2a(whn[cb + 3], p0.w, shn);
        sr = dot2a(whr[cb + 4], p1.x, sr);
        sz = dot2a(whz[cb + 4], p1.x, sz);
        shn = dot2a(whn[cb + 4], p1.x, shn);
        sr = dot2a(whr[cb + 5], p1.y, sr);
        sz = dot2a(whz[cb + 5], p1.y, sz);
        shn = dot2a(whn[cb + 5], p1.y, shn);
        sr = dot2a(whr[cb + 6], p1.z, sr);
        sz = dot2a(whz[cb + 6], p1.z, sz);
        shn = dot2a(whn[cb + 6], p1.z, shn);
        sr = dot2a(whr[cb + 7], p1.w, sr);
        sz = dot2a(whz[cb + 7], p1.w, sz);
        shn = dot2a(whn[cb + 7], p1.w, shn);
        p0 = q0; p1 = q1;
      }

      sr = pair_sum(sr);
      sz = pair_sum(sz);
      shn = pair_sum(shn);

      float r = sigmoid_f(gr + sr);
      float z = sigmoid_f(gz + sz);
      float n = tanh_f(gn + r * (shn + bhn));
      hcur = (1.f - z) * n + z * hcur;

      if (ks == 0) h_buf[(cur ^ 1) * Hn + jg] = (__fp16)hcur;
      __syncthreads();
      cur ^= 1;

      gr = (float)pr; gz = (float)pz; gn = (float)pn;
    }
  }

  if (ks == 0) out[(size_t)b * Hn + jg] = hcur;
}

// ---------------- Fallback (R3): in-kernel phase A, used only if ws too small -------------
template <bool USE_WS>
static __device__ __forceinline__ void phaseA_pass(int col, const unsigned int* __restrict__ w16,
                                                   const float* __restrict__ W_ih,
                                                   const unsigned int* x_lds, float* a) {
  const uint4* wp = (const uint4*)(w16) + (size_t)col * (WU / 4);
  const float* wf = W_ih + (size_t)col * INn;
#pragma unroll 2
  for (int kp = 0; kp < 8; ++kp) {
    uint4 wa, wb;
    if constexpr (USE_WS) {
      wa = wp[2 * kp];
      wb = wp[2 * kp + 1];
    } else {
      const float* f = wf + 16 * kp;
      wa.x = cvt2(f[0], f[1]);   wa.y = cvt2(f[2], f[3]);
      wa.z = cvt2(f[4], f[5]);   wa.w = cvt2(f[6], f[7]);
      wb.x = cvt2(f[8], f[9]);   wb.y = cvt2(f[10], f[11]);
      wb.z = cvt2(f[12], f[13]); wb.w = cvt2(f[14], f[15]);
    }
#pragma unroll
    for (int t = 0; t < Cc; ++t) {
      const uint4* xp = (const uint4*)&x_lds[t * WU + kp * 8];
      uint4 xa = xp[0], xb = xp[1];
      a[t] = dot2(wa.x, xa.x, a[t]);
      a[t] = dot2(wa.y, xa.y, a[t]);
      a[t] = dot2(wa.z, xa.z, a[t]);
      a[t] = dot2(wa.w, xa.w, a[t]);
      a[t] = dot2(wb.x, xb.x, a[t]);
      a[t] = dot2(wb.y, xb.y, a[t]);
      a[t] = dot2(wb.z, xb.z, a[t]);
      a[t] = dot2(wb.w, xb.w, a[t]);
    }
  }
  uint4 wt;
  if constexpr (USE_WS) {
    wt = wp[16];
  } else {
    wt.x = cvt2(wf[128], 0.f); wt.y = 0u; wt.z = 0u; wt.w = 0u;
  }
#pragma unroll
  for (int t = 0; t < Cc; ++t) {
    uint4 xt = *(const uint4*)&x_lds[t * WU + 64];
    a[t] = dot2(wt.x, xt.x, a[t]);
    a[t] = dot2(wt.y, xt.y, a[t]);
  }
}

template <bool USE_WS>
__global__ __launch_bounds__(512, 2)
void gru_scan_fb(const float* __restrict__ times_in, const float* __restrict__ data_in,
                 const float* __restrict__ mask_in, const unsigned int* __restrict__ w16,
                 const float* __restrict__ W_ih, const float* __restrict__ W_hh,
                 const float* __restrict__ b_ih, const float* __restrict__ b_hh,
                 float* __restrict__ out) {
  __shared__ __align__(16) float gx_lds[Cc * 768];
  __shared__ __align__(16) unsigned int x_lds[Cc * WU];
  __shared__ __align__(16) __fp16 h_buf[2 * Hn];
  __shared__ __align__(16) float t_lds[Tn];

  const int tid = threadIdx.x;
  const int b = blockIdx.x;
  const int jg = tid >> 1;
  const int ks = tid & 1;

  t_lds[tid] = times_in[(size_t)b * Tn + tid];

  unsigned int whr[64], whz[64], whn[64];
  {
    const float* w0 = W_hh + (size_t)jg * Hn + ks * 128;
    const float* w1 = W_hh + (size_t)(jg + 256) * Hn + ks * 128;
    const float* w2 = W_hh + (size_t)(jg + 512) * Hn + ks * 128;
#pragma unroll
    for (int c = 0; c < 64; ++c) {
      whr[c] = cvt2(w0[2 * c], w0[2 * c + 1]);
      whz[c] = cvt2(w1[2 * c], w1[2 * c + 1]);
      whn[c] = cvt2(w2[2 * c], w2[2 * c + 1]);
    }
  }
  const float brh = b_hh[jg];
  const float bzh = b_hh[jg + 256];
  const float bhn = b_hh[jg + 512];
  const float bi1 = b_ih[tid];
  const float bi2 = (tid < 256) ? b_ih[512 + tid] : 0.f;

  h_buf[tid] = (__fp16)0.f;
  __syncthreads();

  float hcur = 0.f;
  int cur = 0;
#pragma unroll 1
  for (int ch = 0; ch < NCH; ++ch) {
    const int t0 = ch * Cc;
    {
      int t = tid >> 6;
      int c = tid & 63;
      const float* src = (c < 32)
          ? data_in + ((size_t)b * Tn + t0 + t) * Vn + 2 * c
          : mask_in + ((size_t)b * Tn + t0 + t) * Vn + 2 * (c - 32);
      float2 v = *(const float2*)src;
      x_lds[t * WU + c] = cvt2(v.x, v.y);
      if (tid < Cc) {
        int g = t0 + tid;
        float d = (g < Tn - 1) ? (t_lds[g + 1] - t_lds[g]) : 0.f;
        uint4 tl;
        tl.x = cvt2(d, 0.f); tl.y = 0u; tl.z = 0u; tl.w = 0u;
        *(uint4*)&x_lds[tid * WU + 64] = tl;
      }
    }
    __syncthreads();
    {
      float a[Cc];
#pragma unroll
      for (int t = 0; t < Cc; ++t) a[t] = bi1;
      phaseA_pass<USE_WS>(tid, w16, W_ih, x_lds, a);
#pragma unroll
      for (int t = 0; t < Cc; ++t) gx_lds[t * 768 + tid] = a[t];
      if (tid < 256) {
#pragma unroll
        for (int t = 0; t < Cc; ++t) a[t] = bi2;
        phaseA_pass<USE_WS>(512 + tid, w16, W_ih, x_lds, a);
#pragma unroll
        for (int t = 0; t < Cc; ++t) gx_lds[t * 768 + 512 + tid] = a[t];
      }
    }
    __syncthreads();
    for (int tt = 0; tt < Cc; ++tt) {
      float sr = 0.f, sz = 0.f, shn = 0.f;
      const uint4* hb = (const uint4*)(h_buf + cur * Hn + ks * 128);
#pragma unroll
      for (int c = 0; c < 16; ++c) {
        uint4 hv = hb[c];
        sr = dot2(whr[4 * c + 0], hv.x, sr);
        sz = dot2(whz[4 * c + 0], hv.x, sz);
        shn = dot2(whn[4 * c + 0], hv.x, shn);
        sr = dot2(whr[4 * c + 1], hv.y, sr);
        sz = dot2(whz[4 * c + 1], hv.y, sz);
        shn = dot2(whn[4 * c + 1], hv.y, shn);
        sr = dot2(whr[4 * c + 2], hv.z, sr);
        sz = dot2(whz[4 * c + 2], hv.z, sz);
        shn = dot2(whn[4 * c + 2], hv.z, shn);
        sr = dot2(whr[4 * c + 3], hv.w, sr);
        sz = dot2(whz[4 * c + 3], hv.w, sz);
        shn = dot2(whn[4 * c + 3], hv.w, shn);
      }
      float gxr = gx_lds[tt * 768 + jg];
      float gxz = gx_lds[tt * 768 + 256 + jg];
      float gxn = gx_lds[tt * 768 + 512 + jg];
      sr = pair_sum(sr);
      sz = pair_sum(sz);
      shn = pair_sum(shn);
      float r = sigmoid_f(gxr + sr + brh);
      float z = sigmoid_f(gxz + sz + bzh);
      float n = tanh_f(gxn + r * (shn + bhn));
      float hN = (1.f - z) * n + z * hcur;
      hcur = (t_lds[t0 + tt] > 0.f) ? hN : hcur;
      if (ks == 0) h_buf[(cur ^ 1) * Hn + jg] = (__fp16)hcur;
      __syncthreads();
      cur ^= 1;
    }
  }
  if (ks == 0) out[(size_t)b * Hn + jg] = hcur;
}

extern "C" void kernel_launch(void* const* d_in, const int* in_sizes, int n_in,
                              void* d_out, int out_size, void* d_ws, size_t ws_size,
                              hipStream_t stream) {
  const float* times_in = (const float*)d_in[0];
  const float* data_in = (const float*)d_in[1];
  const float* mask_in = (const float*)d_in[2];
  const float* W_ih = (const float*)d_in[3];
  const float* W_hh = (const float*)d_in[4];
  const float* b_ih = (const float*)d_in[5];
  const float* b_hh = (const float*)d_in[6];
  float* out = (float*)d_out;

  unsigned int* w16 = (unsigned int*)d_ws;
  __fp16* gx = (__fp16*)((char*)d_ws + GX_OFF);

  if (ws_size >= GX_OFF + GX_BYTES) {
    hipLaunchKernelGGL(convert_wih, dim3((WSZ + 255) / 256), dim3(256), 0, stream, W_ih, w16);
    hipLaunchKernelGGL(gx_gemm, dim3(2048, 3), dim3(256), 0, stream,
                       times_in, data_in, mask_in, w16, b_ih, b_hh, gx);
    hipLaunchKernelGGL(gru_scan8, dim3(Bn), dim3(512), 0, stream,
                       times_in, W_hh, b_hh, gx, out);
  } else if (ws_size >= (size_t)WSZ * 4) {
    hipLaunchKernelGGL(convert_wih, dim3((WSZ + 255) / 256), dim3(256), 0, stream, W_ih, w16);
    hipLaunchKernelGGL((gru_scan_fb<true>), dim3(Bn), dim3(512), 0, stream,
                       times_in, data_in, mask_in, w16, W_ih, W_hh, b_ih, b_hh, out);
  } else {
    hipLaunchKernelGGL((gru_scan_fb<false>), dim3(Bn), dim3(512), 0, stream,
                       times_in, data_in, mask_in, (const unsigned int*)nullptr, W_ih, W_hh,
                       b_ih, b_hh, out);
  }
}